// Round 6
// baseline (179.344 us; speedup 1.0000x reference)
//
#include <hip/hip_runtime.h>
#include <hip/hip_fp16.h>
#include <math.h>

typedef _Float16 half8   __attribute__((ext_vector_type(8)));
typedef _Float16 half2v  __attribute__((ext_vector_type(2)));
typedef float    floatx16 __attribute__((ext_vector_type(16)));

#define ROWS   16384
#define DIM    128
#define KCODES 8192
#define NSPLIT 6
#define MTILE  128          // 4 waves x 32 rows
#define LOSS_SCALE (1.0f / ((float)ROWS * (float)DIM))

__device__ __forceinline__ void async_copy16(const _Float16* src, _Float16* dst_lds) {
  __builtin_amdgcn_global_load_lds((const __attribute__((address_space(1))) void*)src,
                                   (__attribute__((address_space(3))) void*)dst_lds,
                                   16, 0, 0);
}

// ---------------- kernel 1: codebook prep (fp16 hi/lo split + (-e2/2)) --------
__global__ __launch_bounds__(256) void prep_codebook(
    const float* __restrict__ cb, _Float16* __restrict__ ehg,
    _Float16* __restrict__ elg, float* __restrict__ e2g)
{
  int tid = threadIdx.x;
  int L = tid & 63;
  int row = blockIdx.x * 4 + (tid >> 6);
  const float2* cr = (const float2*)(cb + (size_t)row * DIM);
  float2 v = cr[L];
  float s2 = v.x * v.x + v.y * v.y;
  #pragma unroll
  for (int m = 1; m < 64; m <<= 1) s2 += __shfl_xor(s2, m);
  if (L == 0) e2g[row] = -0.5f * s2;      // pre-scaled for t = dot - e2/2
  _Float16 h0 = (_Float16)v.x, h1 = (_Float16)v.y;
  half2v hi = {h0, h1};
  half2v lo = {(_Float16)(v.x - (float)h0), (_Float16)(v.y - (float)h1)};
  ((half2v*)(ehg + (size_t)row * DIM))[L] = hi;
  ((half2v*)(elg + (size_t)row * DIM))[L] = lo;
}

// ---------------- kernel 2: LN + argmin via split-fp16 32x32x16 MFMA ----------
// Round-5 evidence: the 8-wave/64KB/160-reg block can never co-reside (occupancy
// pinned at 1 block/CU, MfmaUtil<=45%). This block is 4 waves / 38 KB LDS /
// <=170 regs -> 3 blocks/CU. Wave = 32 rows (32x32x16_f16, 8.07cyc per 32K-MAC
// beats 16x16x32's 4.85 per 16K). NT=32-code double-buffered tile; async
// global_load_lds w16 with XOR swizzle folded into source address; 2 MFMA
// chains/wave (hh and hl+lh), e2 folded in epilogue (v_add3).
// A-frag layout (family of verified 16x16x32): A[m=lane&31][k=(lane>>5)*8+j];
// B mirror; C/D: col=lane&31, row=(reg&3)+8*(reg>>2)+4*(lane>>5) [m74/m101].
__global__ __launch_bounds__(256, 3) void argmin_kernel(
    const float* __restrict__ x, const _Float16* __restrict__ ehg,
    const _Float16* __restrict__ elg, const float* __restrict__ e2g,
    float* __restrict__ best_part, int* __restrict__ idx_part,
    float* __restrict__ x2g)
{
  // [buf][arr(hi/lo)][code n][128 halfs]; 16B chunk at slot cs holds global
  // chunk cs ^ (n&15). 32 KB.
  __shared__ _Float16 ebuf[2][2][32][128];
  __shared__ float e2s[1376];              // split's -e2/2 (<=1376 codes)

  int tid = threadIdx.x;
  int w   = tid >> 6;
  int L   = tid & 63;
  int col = L & 31;      // MFMA A-row(m) / B-col(n) / D-col lane index
  int kh  = L >> 5;      // k-half

  int bx = blockIdx.x;
  int mt = bx & 127;
  int ns = bx >> 7;      // 0..5
  const int soff[7] = {0, 1376, 2752, 4128, 5504, 6848, 8192};
  int code0 = soff[ns];
  int ntile = (soff[ns + 1] - code0) >> 5;   // 43 or 42

  int rowbase = mt * MTILE + w * 32;
  int row = rowbase + col;                   // lanes L and L+32 share a row

  // stage split's e2 (already -e2/2)
  for (int i = tid; i < soff[ns + 1] - code0; i += 256) e2s[i] = e2g[code0 + i];

  // ---- prologue: load row half, LN (partner lane holds other half), pack ----
  const float* xr = x + (size_t)row * DIM + kh * 8;
  float v[64];
  #pragma unroll
  for (int ks = 0; ks < 8; ++ks) {
    float4 p0 = *(const float4*)(xr + ks * 16);
    float4 p1 = *(const float4*)(xr + ks * 16 + 4);
    v[ks*8+0] = p0.x; v[ks*8+1] = p0.y; v[ks*8+2] = p0.z; v[ks*8+3] = p0.w;
    v[ks*8+4] = p1.x; v[ks*8+5] = p1.y; v[ks*8+6] = p1.z; v[ks*8+7] = p1.w;
  }
  float s = 0.f;
  #pragma unroll
  for (int i = 0; i < 64; ++i) s += v[i];
  s += __shfl_xor(s, 32);
  float mu = s * (1.0f / 128.0f);
  float s2 = 0.f;
  #pragma unroll
  for (int i = 0; i < 64; ++i) { float d = v[i] - mu; s2 += d * d; }
  s2 += __shfl_xor(s2, 32);
  float rstd = 1.0f / sqrtf(s2 * (1.0f / 128.0f) + 1e-5f);

  half8 ah[8], al[8];
  float x2 = 0.f;
  #pragma unroll
  for (int ks = 0; ks < 8; ++ks)
    #pragma unroll
    for (int j = 0; j < 8; ++j) {
      float xv = (v[ks*8+j] - mu) * rstd;
      x2 += xv * xv;
      _Float16 h = (_Float16)xv;
      ah[ks][j] = h;
      al[ks][j] = (_Float16)(xv - (float)h);
    }
  x2 += __shfl_xor(x2, 32);
  if (ns == 0 && kh == 0) x2g[row] = x2;     // ||xn||^2 per row (for loss)

  float best[16]; int bch[16];
  #pragma unroll
  for (int r = 0; r < 16; ++r) { best[r] = -3.4e38f; bch[r] = 0; }

  // ---- async staging: 1024 16B chunks per tile, 4 per thread ----
  auto stage = [&](int ch, int p) {
    int cbase = code0 + ch * 32;
    _Float16* lb = &ebuf[p][0][0][0];
    #pragma unroll
    for (int it = 0; it < 4; ++it) {
      int cid = it * 256 + tid;          // 0..1023
      int arr = cid >> 9;                // 0 = hi, 1 = lo
      int lc  = cid & 511;
      int n   = lc >> 4;                 // code slot 0..31
      int cs  = lc & 15;                 // LDS slot chunk
      int cg  = cs ^ (n & 15);           // global chunk (inverse swizzle)
      const _Float16* g = (arr ? elg : ehg) + (size_t)(cbase + n) * DIM + cg * 8;
      async_copy16(g, lb + (size_t)cid * 8);
    }
  };

  stage(0, 0);
  __syncthreads();

  for (int ch = 0; ch < ntile; ++ch) {
    int p = ch & 1;
    if (ch + 1 < ntile) stage(ch + 1, p ^ 1);

    float e2f = e2s[ch * 32 + col];        // -e2/2 of this lane's code column

    floatx16 a0 = {0,0,0,0,0,0,0,0,0,0,0,0,0,0,0,0};
    floatx16 a1 = {0,0,0,0,0,0,0,0,0,0,0,0,0,0,0,0};
    #pragma unroll
    for (int ks = 0; ks < 8; ++ks) {
      int slot = (((ks << 1) | kh) ^ (col & 15)) * 8;
      half8 bh = *(const half8*)&ebuf[p][0][col][slot];
      half8 bl = *(const half8*)&ebuf[p][1][col][slot];
      a0 = __builtin_amdgcn_mfma_f32_32x32x16_f16(ah[ks], bh, a0, 0, 0, 0);
      a1 = __builtin_amdgcn_mfma_f32_32x32x16_f16(ah[ks], bl, a1, 0, 0, 0);
      a1 = __builtin_amdgcn_mfma_f32_32x32x16_f16(al[ks], bh, a1, 0, 0, 0);
    }
    #pragma unroll
    for (int r = 0; r < 16; ++r) {
      float t = (a0[r] + a1[r]) + e2f;     // t = dot - e2/2 (maximize)
      if (t > best[r]) { best[r] = t; bch[r] = ch; }
    }
    __syncthreads();   // drains async stage of ch+1; protects buf reuse
  }

  // ---- final: full index, reduce over 32 code-columns, write partials ----
  int ibase = code0 + col;
  #pragma unroll
  for (int r = 0; r < 16; ++r) {
    float b = best[r];
    int   bi = (bch[r] << 5) + ibase;
    #pragma unroll
    for (int m = 1; m < 32; m <<= 1) {
      float ob = __shfl_xor(b, m);
      int   oi = __shfl_xor(bi, m);
      if (ob > b || (ob == b && oi < bi)) { b = ob; bi = oi; }
    }
    if (col == 0) {
      int rw = rowbase + (r & 3) + ((r >> 2) << 3) + (kh << 2);
      best_part[(size_t)rw * NSPLIT + ns] = b;
      idx_part [(size_t)rw * NSPLIT + ns] = bi;
    }
  }
}

// ---------------- kernel 3: merge + gather + per-block loss partial ----------
// 32 rows/block. loss per row = ||xn||^2 - 2*t_best.
__global__ __launch_bounds__(256) void gather_loss_kernel(
    const float* __restrict__ cb, const float* __restrict__ best_part,
    const int* __restrict__ idx_part, const float* __restrict__ x2g,
    float* __restrict__ out_q, float* __restrict__ out_ind,
    float* __restrict__ loss_part)
{
  __shared__ int   sidx[32];
  __shared__ float sloss[32];
  int tid = threadIdx.x;
  int rb = blockIdx.x * 32;
  int r = tid >> 3, k = tid & 7;
  int row = rb + r;

  float b  = -3.4e38f; int bi = 0x7fffffff;
  if (k < NSPLIT) {
    b  = best_part[(size_t)row * NSPLIT + k];
    bi = idx_part [(size_t)row * NSPLIT + k];
  }
  #pragma unroll
  for (int m = 1; m < 8; m <<= 1) {
    float ob = __shfl_xor(b, m);
    int   oi = __shfl_xor(bi, m);
    if (ob > b || (ob == b && oi < bi)) { b = ob; bi = oi; }
  }
  if (k == 0) {
    sidx[r] = bi;
    out_ind[row] = (float)bi;
    sloss[r] = x2g[row] - 2.0f * b;
  }
  __syncthreads();

  if (tid < 32) {
    float sl = sloss[tid];
    #pragma unroll
    for (int m = 1; m < 32; m <<= 1) sl += __shfl_xor(sl, m);
    if (tid == 0) loss_part[blockIdx.x] = sl;
  }

  // copy 32 codebook rows (512B each) to out_q
  const float4* cb4 = (const float4*)cb;
  float4* oq4 = (float4*)out_q;
  #pragma unroll
  for (int it = 0; it < 4; ++it) {
    int idx = it * 256 + tid;          // 0..1023
    int r2 = idx >> 5, c4 = idx & 31;
    oq4[(size_t)(rb + r2) * 32 + c4] = cb4[(size_t)sidx[r2] * 32 + c4];
  }
}

// ---------------- kernel 4: deterministic loss reduction (512 partials) ------
__global__ __launch_bounds__(256) void loss_reduce_kernel(
    const float* __restrict__ loss_part, float* __restrict__ out_loss)
{
  __shared__ float sm[256];
  int tid = threadIdx.x;
  float s = loss_part[tid] + loss_part[tid + 256];
  sm[tid] = s; __syncthreads();
  for (int st = 128; st > 0; st >>= 1) {
    if (tid < st) sm[tid] += sm[tid + st];
    __syncthreads();
  }
  if (tid == 0) *out_loss = sm[0] * LOSS_SCALE;
}

extern "C" void kernel_launch(void* const* d_in, const int* in_sizes, int n_in,
                              void* d_out, int out_size, void* d_ws, size_t ws_size,
                              hipStream_t stream)
{
  const float* x  = (const float*)d_in[0];   // [4,4096,128] fp32
  const float* cb = (const float*)d_in[1];   // [8192,128]  fp32

  char* ws = (char*)d_ws;
  _Float16* ehg      = (_Float16*)(ws + 0);          // 2 MB
  _Float16* elg      = (_Float16*)(ws + 2097152);    // 2 MB
  float*    e2g      = (float*)   (ws + 4194304);    // 32 KB
  float*    best_part= (float*)   (ws + 4227072);    // 384 KB
  int*      idx_part = (int*)     (ws + 4620288);    // 384 KB
  float*    x2g      = (float*)   (ws + 5013504);    // 64 KB
  float*    loss_part= (float*)   (ws + 5079040);    // 2 KB

  float* out_q    = (float*)d_out;                   // 16384*128
  float* out_ind  = out_q + (size_t)ROWS * DIM;      // 16384 (as float)
  float* out_loss = out_ind + ROWS;                  // 1

  prep_codebook<<<KCODES / 4, 256, 0, stream>>>(cb, ehg, elg, e2g);
  argmin_kernel<<<(ROWS / MTILE) * NSPLIT, 256, 0, stream>>>(x, ehg, elg, e2g, best_part, idx_part, x2g);
  gather_loss_kernel<<<ROWS / 32, 256, 0, stream>>>(cb, best_part, idx_part, x2g, out_q, out_ind, loss_part);
  loss_reduce_kernel<<<1, 256, 0, stream>>>(loss_part, out_loss);
}